// Round 1
// baseline (310.682 us; speedup 1.0000x reference)
//
#include <hip/hip_runtime.h>
#include <math.h>

// MeanShift: x (2,3,96,96) fp32. N=9216 pts/batch, C=3, 5 iterations of
// all-pairs Gaussian-weighted mean against ORIGINAL points.
//
// Coordinates are pre-scaled by s = sqrt(50 * log2e) so
//   exp(-50*d2) == exp2(-||s*y - s*x||^2)  -> native v_exp_f32, no extra mul.
// y is kept in scaled space across iterations; unscaled only in ms_pack.

#define NPTS   9216            // 96*96
#define NB     2               // batch
#define MSPLIT 8               // m-slices (blocks per n-tile)
#define SLICE  (NPTS / MSPLIT) // 1152 points per block's m-slice
#define WSLICE (SLICE / 4)     // 288 per wave (wave-uniform LDS broadcast)
#define NTILES (NPTS / 64)     // 144 n-tiles per batch
#define INV2BW2 50.0f          // 1/(2*0.1^2)
#define LOG2E   1.44269504088896340736f

// partial layout: part[(b*NPTS + n)*MSPLIT + k] = float4(num0,num1,num2,den)

__global__ __launch_bounds__(256) void ms_init(const float* __restrict__ x,
                                               float4* __restrict__ part,
                                               float s) {
    int gid = blockIdx.x * 256 + threadIdx.x;   // 0..18431
    int b = gid / NPTS;
    int n = gid - b * NPTS;
    const float* xb = x + b * 3 * NPTS;
    float4 p0;
    p0.x = xb[n] * s;
    p0.y = xb[NPTS + n] * s;
    p0.z = xb[2 * NPTS + n] * s;
    p0.w = 1.0f;                                // den=1 -> y0 = s*x
    float4* dst = part + (size_t)gid * MSPLIT;
    dst[0] = p0;
    float4 z = make_float4(0.f, 0.f, 0.f, 0.f);
#pragma unroll
    for (int k = 1; k < MSPLIT; ++k) dst[k] = z;
}

__global__ __launch_bounds__(256) void ms_iter(const float* __restrict__ x,
                                               const float4* __restrict__ pin,
                                               float4* __restrict__ pout,
                                               float s) {
    __shared__ float4 pts[SLICE];   // 18 KB: this block's scaled m-slice
    __shared__ float4 red[256];     // 4 KB: cross-wave reduction

    const int tid  = threadIdx.x;
    const int lane = tid & 63;
    const int wv   = tid >> 6;
    const int k    = blockIdx.x & (MSPLIT - 1);
    const int tile = blockIdx.x >> 3;           // MSPLIT == 8
    const int b    = tile / NTILES;
    const int nt   = tile - b * NTILES;
    const int n    = nt * 64 + lane;
    const float* xb = x + b * 3 * NPTS;
    const int mbeg = k * SLICE;

    // Stage this block's m-slice into LDS, scaled.
    for (int i = tid; i < SLICE; i += 256) {
        int g = mbeg + i;
        float4 p;
        p.x = xb[g] * s;
        p.y = xb[NPTS + g] * s;
        p.z = xb[2 * NPTS + g] * s;
        p.w = 0.f;
        pts[i] = p;
    }

    // Combine previous step's 8 partials -> current y (scaled space).
    // (Overlaps with LDS staging latency; redundant across the 4 waves, cheap.)
    const float4* src = pin + (size_t)(b * NPTS + n) * MSPLIT;
    float n0 = 0.f, n1 = 0.f, n2 = 0.f, dn = 0.f;
#pragma unroll
    for (int kk = 0; kk < MSPLIT; ++kk) {
        float4 p = src[kk];
        n0 += p.x; n1 += p.y; n2 += p.z; dn += p.w;
    }
    float inv = 1.0f / dn;
    const float y0 = n0 * inv, y1 = n1 * inv, y2 = n2 * inv;

    __syncthreads();

    // Hot loop: 288 m's per thread, wave-uniform LDS address (broadcast).
    float a0 = 0.f, a1 = 0.f, a2 = 0.f, ad = 0.f;
    const float4* pw = pts + wv * WSLICE;
#pragma unroll 8
    for (int i = 0; i < WSLICE; ++i) {
        float4 p = pw[i];
        float dx = y0 - p.x;
        float dy = y1 - p.y;
        float dz = y2 - p.z;
        float t = fmaf(dz, dz, fmaf(dy, dy, dx * dx));
        float w = __builtin_amdgcn_exp2f(-t);   // exp(-50*d2), neg is free modifier
        a0 = fmaf(w, p.x, a0);
        a1 = fmaf(w, p.y, a1);
        a2 = fmaf(w, p.z, a2);
        ad += w;
    }

    red[tid] = make_float4(a0, a1, a2, ad);
    __syncthreads();
    if (tid < 64) {
        float4 r0 = red[tid];
        float4 r1 = red[64 + tid];
        float4 r2 = red[128 + tid];
        float4 r3 = red[192 + tid];
        float4 o;
        o.x = (r0.x + r1.x) + (r2.x + r3.x);
        o.y = (r0.y + r1.y) + (r2.y + r3.y);
        o.z = (r0.z + r1.z) + (r2.z + r3.z);
        o.w = (r0.w + r1.w) + (r2.w + r3.w);
        pout[(size_t)(b * NPTS + n) * MSPLIT + k] = o;
    }
}

__global__ __launch_bounds__(256) void ms_pack(const float4* __restrict__ part,
                                               float* __restrict__ out,
                                               float invs) {
    int gid = blockIdx.x * 256 + threadIdx.x;
    int b = gid / NPTS;
    int n = gid - b * NPTS;
    const float4* src = part + (size_t)gid * MSPLIT;
    float n0 = 0.f, n1 = 0.f, n2 = 0.f, dn = 0.f;
#pragma unroll
    for (int kk = 0; kk < MSPLIT; ++kk) {
        float4 p = src[kk];
        n0 += p.x; n1 += p.y; n2 += p.z; dn += p.w;
    }
    float f = invs / dn;                        // unscale + normalize
    float* ob = out + b * 3 * NPTS;
    ob[n]            = n0 * f;
    ob[NPTS + n]     = n1 * f;
    ob[2 * NPTS + n] = n2 * f;
}

extern "C" void kernel_launch(void* const* d_in, const int* in_sizes, int n_in,
                              void* d_out, int out_size, void* d_ws, size_t ws_size,
                              hipStream_t stream) {
    const float* x = (const float*)d_in[0];
    float* out = (float*)d_out;
    const float s = sqrtf(INV2BW2 * LOG2E);     // 8.4932...

    float4* pa = (float4*)d_ws;                                  // 2.36 MB
    float4* pb = pa + (size_t)NB * NPTS * MSPLIT;                // 2.36 MB

    ms_init<<<NB * NPTS / 256, 256, 0, stream>>>(x, pa, s);
    float4* cur = pa;
    float4* nxt = pb;
    for (int it = 0; it < 5; ++it) {
        ms_iter<<<NB * NTILES * MSPLIT, 256, 0, stream>>>(x, cur, nxt, s);
        float4* t = cur; cur = nxt; nxt = t;
    }
    ms_pack<<<NB * NPTS / 256, 256, 0, stream>>>(cur, out, 1.0f / s);
}

// Round 2
// 290.165 us; speedup vs baseline: 1.0707x; 1.0707x over previous
//
#include <hip/hip_runtime.h>
#include <math.h>

// MeanShift: x (2,3,96,96) fp32. N=9216 pts/batch, C=3, 5 iterations of
// all-pairs Gaussian-weighted mean against ORIGINAL points.
//
// Scaled space: s = sqrt(50*log2e), so exp(-50*d2) == exp2(-||sy - sx||^2).
// Distance via dot form (matches reference):
//   u = 2y.p - |y|^2 - |p|^2 ; w = exp2(u)
// with -|p|^2 pre-staged in p.w -> 8 VALU + 1 exp per pair.
// Each thread handles TWO y's (n and n+64) to amortize the LDS load.

#define NPTS   9216            // 96*96
#define NB     2
#define MSPLIT 12              // m-slices per n-tile
#define SLICE  (NPTS / MSPLIT) // 768 m-points per block
#define WSLICE (SLICE / 4)     // 192 m-points per wave/thread
#define NPB    128             // n-points per block (2 per thread)
#define NTILES (NPTS / NPB)    // 72
#define INV2BW2 50.0f
#define LOG2E   1.44269504088896340736f

// partial layout: part[(b*NPTS + n)*MSPLIT + k] = float4(num0,num1,num2,den)

__global__ __launch_bounds__(256) void ms_init(const float* __restrict__ x,
                                               float4* __restrict__ part,
                                               float s) {
    int gid = blockIdx.x * 256 + threadIdx.x;   // 0..18431
    int b = gid / NPTS;
    int n = gid - b * NPTS;
    const float* xb = x + b * 3 * NPTS;
    float4 p0;
    p0.x = xb[n] * s;
    p0.y = xb[NPTS + n] * s;
    p0.z = xb[2 * NPTS + n] * s;
    p0.w = 1.0f;                                // den=1 -> y0 = s*x
    float4* dst = part + (size_t)gid * MSPLIT;
    dst[0] = p0;
    float4 z = make_float4(0.f, 0.f, 0.f, 0.f);
#pragma unroll
    for (int k = 1; k < MSPLIT; ++k) dst[k] = z;
}

__global__ __launch_bounds__(256) void ms_iter(const float* __restrict__ x,
                                               const float4* __restrict__ pin,
                                               float4* __restrict__ pout,
                                               float s) {
    __shared__ float4 buf[SLICE];   // 12 KB; reused as reduction scratch

    const int tid  = threadIdx.x;
    const int lane = tid & 63;
    const int wv   = tid >> 6;
    const int k    = blockIdx.x % MSPLIT;
    const int tile = blockIdx.x / MSPLIT;
    const int b    = tile / NTILES;
    const int nt   = tile - b * NTILES;
    const int nbase = nt * NPB;
    const float* xb = x + b * 3 * NPTS;
    const int mbeg = k * SLICE;

    // Stage this block's m-slice into LDS, scaled, with w = -|p|^2.
    for (int i = tid; i < SLICE; i += 256) {
        int g = mbeg + i;
        float px = xb[g] * s;
        float py = xb[NPTS + g] * s;
        float pz = xb[2 * NPTS + g] * s;
        float4 p;
        p.x = px; p.y = py; p.z = pz;
        p.w = -fmaf(px, px, fmaf(py, py, pz * pz));
        buf[i] = p;
    }

    // Combine previous partials -> two current y's (scaled space).
    const float4* srcA = pin + (size_t)(b * NPTS + nbase + lane) * MSPLIT;
    const float4* srcB = srcA + (size_t)64 * MSPLIT;
    float nA0=0,nA1=0,nA2=0,dA=0, nB0=0,nB1=0,nB2=0,dB=0;
#pragma unroll
    for (int kk = 0; kk < MSPLIT; ++kk) {
        float4 a = srcA[kk];
        float4 c = srcB[kk];
        nA0+=a.x; nA1+=a.y; nA2+=a.z; dA+=a.w;
        nB0+=c.x; nB1+=c.y; nB2+=c.z; dB+=c.w;
    }
    const float invA = 1.0f / dA, invB = 1.0f / dB;
    const float yA0=nA0*invA, yA1=nA1*invA, yA2=nA2*invA;
    const float yB0=nB0*invB, yB1=nB1*invB, yB2=nB2*invB;
    const float mA0=2.f*yA0, mA1=2.f*yA1, mA2=2.f*yA2;
    const float mB0=2.f*yB0, mB1=2.f*yB1, mB2=2.f*yB2;
    const float cA = -fmaf(yA0,yA0,fmaf(yA1,yA1,yA2*yA2));  // -|y|^2
    const float cB = -fmaf(yB0,yB0,fmaf(yB1,yB1,yB2*yB2));

    __syncthreads();

    // Hot loop: 192 m's, 2 y's per thread; wave-uniform LDS broadcast.
    float a00=0,a01=0,a02=0,a03=0, a10=0,a11=0,a12=0,a13=0;
    const float4* pw = buf + wv * WSLICE;
#pragma unroll 4
    for (int i = 0; i < WSLICE; ++i) {
        float4 p = pw[i];
        float uA = fmaf(p.x, mA0, fmaf(p.y, mA1, fmaf(p.z, mA2, p.w + cA)));
        float uB = fmaf(p.x, mB0, fmaf(p.y, mB1, fmaf(p.z, mB2, p.w + cB)));
        float wA = __builtin_amdgcn_exp2f(uA);
        float wB = __builtin_amdgcn_exp2f(uB);
        a00 = fmaf(wA, p.x, a00); a01 = fmaf(wA, p.y, a01);
        a02 = fmaf(wA, p.z, a02); a03 += wA;
        a10 = fmaf(wB, p.x, a10); a11 = fmaf(wB, p.y, a11);
        a12 = fmaf(wB, p.z, a12); a13 += wB;
    }

    // Cross-wave reduction, reusing buf (512 float4 <= 768).
    __syncthreads();
    buf[wv * NPB + lane]      = make_float4(a00, a01, a02, a03);
    buf[wv * NPB + 64 + lane] = make_float4(a10, a11, a12, a13);
    __syncthreads();
    if (tid < NPB) {
        float4 r0 = buf[tid];
        float4 r1 = buf[NPB + tid];
        float4 r2 = buf[2 * NPB + tid];
        float4 r3 = buf[3 * NPB + tid];
        float4 o;
        o.x = (r0.x + r1.x) + (r2.x + r3.x);
        o.y = (r0.y + r1.y) + (r2.y + r3.y);
        o.z = (r0.z + r1.z) + (r2.z + r3.z);
        o.w = (r0.w + r1.w) + (r2.w + r3.w);
        pout[(size_t)(b * NPTS + nbase + tid) * MSPLIT + k] = o;
    }
}

__global__ __launch_bounds__(256) void ms_pack(const float4* __restrict__ part,
                                               float* __restrict__ out,
                                               float invs) {
    int gid = blockIdx.x * 256 + threadIdx.x;
    int b = gid / NPTS;
    int n = gid - b * NPTS;
    const float4* src = part + (size_t)gid * MSPLIT;
    float n0 = 0.f, n1 = 0.f, n2 = 0.f, dn = 0.f;
#pragma unroll
    for (int kk = 0; kk < MSPLIT; ++kk) {
        float4 p = src[kk];
        n0 += p.x; n1 += p.y; n2 += p.z; dn += p.w;
    }
    float f = invs / dn;                        // unscale + normalize
    float* ob = out + b * 3 * NPTS;
    ob[n]            = n0 * f;
    ob[NPTS + n]     = n1 * f;
    ob[2 * NPTS + n] = n2 * f;
}

extern "C" void kernel_launch(void* const* d_in, const int* in_sizes, int n_in,
                              void* d_out, int out_size, void* d_ws, size_t ws_size,
                              hipStream_t stream) {
    const float* x = (const float*)d_in[0];
    float* out = (float*)d_out;
    const float s = sqrtf(INV2BW2 * LOG2E);     // 8.4932...

    float4* pa = (float4*)d_ws;                                  // 3.54 MB
    float4* pb = pa + (size_t)NB * NPTS * MSPLIT;                // 3.54 MB

    ms_init<<<NB * NPTS / 256, 256, 0, stream>>>(x, pa, s);
    float4* cur = pa;
    float4* nxt = pb;
    for (int it = 0; it < 5; ++it) {
        ms_iter<<<NB * NTILES * MSPLIT, 256, 0, stream>>>(x, cur, nxt, s);
        float4* t = cur; cur = nxt; nxt = t;
    }
    ms_pack<<<NB * NPTS / 256, 256, 0, stream>>>(cur, out, 1.0f / s);
}